// Round 1
// baseline (189.825 us; speedup 1.0000x reference)
//
#include <hip/hip_runtime.h>

// AdderNet 2D "conv": out[n,co,ho,wo] = -sum_{ci,kh,kw} |x_pad - w|
// x: [16,64,56,56] f32, w: [64,64,3,3] f32, out: [16,64,56,56] f32
// VALU-bound: 2 f32 ops per reduce element (sub + add with |.| modifier).

#define TS    8      // spatial tile 8x8
#define HALO  10     // TS + 2 halo
#define LDSW  12     // padded LDS row stride (<=2-way bank aliasing: free)
#define NCI   64
#define COPT  16     // co channels per thread (per-wave co set -> scalar w loads)

__global__ __launch_bounds__(256, 4) void adder2d_kernel(
    const float* __restrict__ x, const float* __restrict__ w,
    float* __restrict__ out)
{
    __shared__ float xs[NCI][HALO][LDSW];

    const int bid = blockIdx.x;
    const int n   = bid / 49;
    const int t   = bid % 49;
    const int h0  = (t / 7) * TS;
    const int w0  = (t % 7) * TS;

    const int tid = threadIdx.x;

    // ---- stage padded x tile into LDS (zero halo at image borders) ----
    const float* xn = x + (size_t)n * NCI * 56 * 56;
    for (int idx = tid; idx < NCI * HALO * HALO; idx += 256) {
        int ci = idx / (HALO * HALO);
        int rc = idx % (HALO * HALO);
        int r  = rc / HALO;
        int c  = rc % HALO;
        int gh = h0 + r - 1;
        int gw = w0 + c - 1;
        float v = 0.f;
        if ((unsigned)gh < 56u && (unsigned)gw < 56u)
            v = xn[(ci * 56 + gh) * 56 + gw];
        xs[ci][r][c] = v;
    }
    __syncthreads();

    // ---- compute: lane = spatial position, wave = 16-co slice ----
    const int lane = tid & 63;
    const int py   = lane >> 3;
    const int px   = lane & 7;
    // wave-uniform co base -> weight loads become s_load (scalar pipe)
    const int co_base = __builtin_amdgcn_readfirstlane((tid >> 6) * COPT);
    const float* __restrict__ wb = w + (size_t)co_base * (NCI * 9);

    float acc[COPT];
    #pragma unroll
    for (int i = 0; i < COPT; ++i) acc[i] = 0.f;

    for (int ci = 0; ci < NCI; ++ci) {
        #pragma unroll
        for (int kh = 0; kh < 3; ++kh) {
            #pragma unroll
            for (int kw = 0; kw < 3; ++kw) {
                const float xv = xs[ci][py + kh][px + kw];
                const int m = ci * 9 + kh * 3 + kw;
                #pragma unroll
                for (int i = 0; i < COPT; ++i) {
                    acc[i] += fabsf(xv - wb[i * (NCI * 9) + m]);
                }
            }
        }
    }

    // ---- epilogue ----
    float* on = out + ((size_t)n * 64 + co_base) * 56 * 56;
    const int off = (h0 + py) * 56 + (w0 + px);
    #pragma unroll
    for (int i = 0; i < COPT; ++i) {
        on[i * 56 * 56 + off] = -acc[i];
    }
}

extern "C" void kernel_launch(void* const* d_in, const int* in_sizes, int n_in,
                              void* d_out, int out_size, void* d_ws, size_t ws_size,
                              hipStream_t stream) {
    const float* x = (const float*)d_in[0];
    const float* w = (const float*)d_in[1];
    float* out = (float*)d_out;
    // grid: 16 images * 7*7 spatial tiles
    dim3 grid(16 * 49);
    dim3 block(256);
    adder2d_kernel<<<grid, block, 0, stream>>>(x, w, out);
}

// Round 2
// 147.647 us; speedup vs baseline: 1.2857x; 1.2857x over previous
//
#include <hip/hip_runtime.h>

// AdderNet 2D: out[n,co,ho,wo] = -sum_{ci,kh,kw} |x_pad[n,ci,ho+kh-1,wo+kw-1] - w[co,ci,kh,kw]|
// x: [16,64,56,56] f32, w: [64,64,3,3] f32, out: [16,64,56,56] f32.
// VALU-bound (no MFMA possible for |.|). Floor: 2 f32 ops/reduce-elem = ~47 us.
//
// Structure: lane = co (64 lanes = 64 output channels). Wave = one 8-wide row
// segment of outputs. Weights: per-lane coalesced float4 loads from a
// pre-transposed w_t[ci][k4][co][4] in d_ws. x: block-staged LDS tile, read
// as wave-uniform broadcast (conflict-free) into registers, reused 9 taps.

#define NCI   64
#define TR    4     // output rows per block (one per wave)
#define TC    8     // output cols per block/wave
#define LDSW  12    // padded LDS row stride (floats, 48B -> float4 aligned)

// ---- pre-kernel: transpose w[co][ci][k] -> w_t[ci][k4][co][4] (k = k4*4+j) ----
__global__ void wt_transpose_kernel(const float* __restrict__ w, float* __restrict__ wt) {
    int idx = blockIdx.x * 256 + threadIdx.x;   // over 64*3*64*4 = 49152 slots
    if (idx >= NCI * 3 * 64 * 4) return;
    int ci  = idx / 768;
    int rem = idx % 768;
    int k4  = rem / 256;
    int r2  = rem % 256;
    int co  = r2 / 4;
    int jj  = r2 % 4;
    int k   = k4 * 4 + jj;
    wt[idx] = (k < 9) ? w[(co * NCI + ci) * 9 + k] : 0.0f;
}

template <bool USE_WT>
__global__ __launch_bounds__(256, 6) void adder2d_main(
    const float* __restrict__ x, const float* __restrict__ w,
    const float* __restrict__ wt, float* __restrict__ out)
{
    __shared__ float xs[NCI][TR + 2][LDSW];   // 64 x 6 x 12 f32 = 18 KiB

    const int bid = blockIdx.x;
    const int n   = bid / 98;          // 14*7 = 98 tiles per image
    const int t   = bid % 98;
    const int r0  = (t / 7) * TR;
    const int c0  = (t % 7) * TC;

    const int tid  = threadIdx.x;
    const int lane = tid & 63;         // = co
    const int wv   = tid >> 6;         // wave id 0..3 = output row within tile

    // ---- stage x tile: rows r0-1..r0+4 (6), cols c0-1..c0+8 (10), all ci ----
    const float* xn = x + (size_t)n * NCI * 56 * 56;
    for (int idx = tid; idx < NCI * 6 * 10; idx += 256) {
        int ci  = idx / 60;
        int rem = idx % 60;
        int r   = rem / 10;
        int c   = rem % 10;
        int gh  = r0 + r - 1;
        int gw  = c0 + c - 1;
        float v = 0.f;
        if ((unsigned)gh < 56u && (unsigned)gw < 56u)
            v = xn[(ci * 56 + gh) * 56 + gw];
        xs[ci][r][c] = v;
    }
    __syncthreads();

    float acc[TC];
    #pragma unroll
    for (int s = 0; s < TC; ++s) acc[s] = 0.f;

    const float4* wt4 = (const float4*)wt;   // [ci][k4][co] float4

    for (int ci = 0; ci < NCI; ++ci) {
        // per-lane weights for this ci: 9 taps (+3 pad) as 3 coalesced float4
        float wreg[12];
        if (USE_WT) {
            #pragma unroll
            for (int k4 = 0; k4 < 3; ++k4) {
                float4 q = wt4[(ci * 3 + k4) * 64 + lane];
                wreg[k4 * 4 + 0] = q.x; wreg[k4 * 4 + 1] = q.y;
                wreg[k4 * 4 + 2] = q.z; wreg[k4 * 4 + 3] = q.w;
            }
        } else {
            #pragma unroll
            for (int k = 0; k < 9; ++k)
                wreg[k] = w[(lane * NCI + ci) * 9 + k];
        }

        // wave-uniform broadcast read of the 3x10 x patch into registers
        float xp[3][10];
        #pragma unroll
        for (int dr = 0; dr < 3; ++dr) {
            const float* row = &xs[ci][wv + dr][0];
            float4 A = *(const float4*)(row);
            float4 B = *(const float4*)(row + 4);
            float2 C = *(const float2*)(row + 8);
            xp[dr][0] = A.x; xp[dr][1] = A.y; xp[dr][2] = A.z; xp[dr][3] = A.w;
            xp[dr][4] = B.x; xp[dr][5] = B.y; xp[dr][6] = B.z; xp[dr][7] = B.w;
            xp[dr][8] = C.x; xp[dr][9] = C.y;
        }

        // 9 taps x 8 positions: 144 essential VALU
        #pragma unroll
        for (int k = 0; k < 9; ++k) {
            const int kh = k / 3, kw = k % 3;
            const float wval = wreg[k];
            #pragma unroll
            for (int s = 0; s < TC; ++s)
                acc[s] += fabsf(xp[kh][s + kw] - wval);
        }
    }

    // ---- epilogue: per-lane 8 contiguous floats -> two float4 stores ----
    float* op = out + (((size_t)n * 64 + lane) * 56 + (r0 + wv)) * 56 + c0;
    float4 o0 = make_float4(-acc[0], -acc[1], -acc[2], -acc[3]);
    float4 o1 = make_float4(-acc[4], -acc[5], -acc[6], -acc[7]);
    *(float4*)(op)     = o0;
    *(float4*)(op + 4) = o1;
}

extern "C" void kernel_launch(void* const* d_in, const int* in_sizes, int n_in,
                              void* d_out, int out_size, void* d_ws, size_t ws_size,
                              hipStream_t stream) {
    const float* x = (const float*)d_in[0];
    const float* w = (const float*)d_in[1];
    float* out = (float*)d_out;
    float* wt  = (float*)d_ws;

    const size_t wt_bytes = (size_t)NCI * 3 * 64 * 4 * sizeof(float);  // 192 KiB
    const bool use_wt = ws_size >= wt_bytes;

    if (use_wt) {
        wt_transpose_kernel<<<(NCI * 3 * 64 * 4 + 255) / 256, 256, 0, stream>>>(w, wt);
        adder2d_main<true><<<16 * 98, 256, 0, stream>>>(x, w, wt, out);
    } else {
        adder2d_main<false><<<16 * 98, 256, 0, stream>>>(x, w, wt, out);
    }
}